// Round 9
// baseline (613.714 us; speedup 1.0000x reference)
//
#include <hip/hip_runtime.h>
#include <hip/hip_bf16.h>

#define N_NODESC 100000
#define N_EDGESC 1000000
#define N_QUERYC 100000

typedef short short8 __attribute__((ext_vector_type(8)));
typedef short s16x2 __attribute__((ext_vector_type(2)));
typedef float f32x4 __attribute__((ext_vector_type(4)));

// ---------- dual-dtype load helper (flag: 1 = inputs are bf16, 0 = f32) ----------
__device__ __forceinline__ float ldf(const void* p, int i, int isbf) {
  return isbf ? __bfloat162float(((const __hip_bfloat16*)p)[i])
              : ((const float*)p)[i];
}
__device__ __forceinline__ unsigned short f2b(float x) {
  __hip_bfloat16 h = __float2bfloat16(x);
  return *(unsigned short*)&h;
}
__device__ __forceinline__ s16x2 u2s(unsigned u) {
  union { unsigned u; s16x2 s; } c; c.u = u; return c.s;
}
__device__ __forceinline__ void gload16(const void* g, void* l) {
  __builtin_amdgcn_global_load_lds(
      (const __attribute__((address_space(1))) void*)g,
      (__attribute__((address_space(3))) void*)l, 16, 0, 0);
}

// ---------- 0: fused setup — cnt zeroing ∪ sniff ∪ BOTH weight swizzles ----------
// blocks [0,nz): zero cnt; block nz: sniff -> *flag; blocks (nz, nz+128]:
// weff (layer = wb>>6), each deriving isbf LOCALLY (8KB sniff from L2) to
// avoid an intra-kernel dependency on *flag.
__global__ __launch_bounds__(256) void k_setup(
    const void* x, int* flag, int* cnt, int n,
    const void* W1, const void* b1, const void* W2, const void* b2,
    unsigned short* __restrict__ Wq1, float* __restrict__ bcat1,
    unsigned short* __restrict__ Wq2, float* __restrict__ bcat2, int nzBlocks) {
  int bid = blockIdx.x;
  int t = threadIdx.x;
  if (bid < nzBlocks) {
    int i = bid * 256 + t;
    if (i < n) cnt[i] = 0;
    return;
  }
  // local sniff (deterministic, same result in every block)
  __shared__ int scnt;
  if (t == 0) scnt = 0;
  __syncthreads();
  const unsigned short* h = (const unsigned short*)x;
  int local = 0;
  for (int i = t; i < 4096; i += 256) {
    int e = (h[i] >> 7) & 0xFF;
    if (e >= 107 && e <= 133) local++;
  }
  atomicAdd(&scnt, local);
  __syncthreads();
  int isbf = (scnt >= 3482) ? 1 : 0;
  if (bid == nzBlocks) {
    if (t == 0) *flag = isbf;
    return;
  }
  int wb = bid - nzBlocks - 1;  // 0..127
  int layer = wb >> 6;
  const void* W = layer ? W2 : W1;
  const void* b = layer ? b2 : b1;
  unsigned short* Wq = layer ? Wq2 : Wq1;
  float* bcat = layer ? bcat2 : bcat1;
  int tt = (wb & 63) * 256 + t;  // 0..16383
  int w4 = tt >> 12;
  int hh = (tt >> 6) & 63;
  int kk = tt & 63;
  int s = (kk >> 3) ^ (hh & 7);
  Wq[(w4 * 64 + hh) * 64 + s * 8 + (kk & 7)] = f2b(ldf(W, w4 * 4096 + kk * 64 + hh, isbf));
  if (tt < 256) bcat[tt] = ldf(b, tt, isbf);
}

// ---------- 1: fused single-atomic-pass fill0 ∪ interleave inputs ----------
// R8 verified: 1M random device atomics ~ 70us regardless of padding (write-
// through RMW, ~30MB sector writebacks). Unpadded counters (control: if this
// kernel regresses >105us, padding mattered and gets restored).
__global__ __launch_bounds__(256) void k_fill0_ilv(
    const int* __restrict__ ei,
    const void* nr, const void* ni, const void* nj, const void* nk,
    int* __restrict__ cnt, uint4* __restrict__ temp, int ne, int fillBlocks,
    const void* X0, const void* X1, const void* X2, const void* X3,
    const int* __restrict__ flagp, unsigned short* __restrict__ Xg, int n) {
  int bid = blockIdx.x;
  if (bid < fillBlocks) {
    int isbf = *flagp;
    int e = bid * 256 + threadIdx.x;
    if (e >= ne) return;
    int s = ei[e];
    int d = ei[ne + e];
    int pos = atomicAdd(&cnt[d], 1);
    uint4 r;
    r.x = (unsigned)s;
    r.y = (unsigned)f2b(-ldf(nr, e, isbf)) | ((unsigned)f2b(-ldf(ni, e, isbf)) << 16);
    r.z = (unsigned)f2b(-ldf(nj, e, isbf)) | ((unsigned)f2b(-ldf(nk, e, isbf)) << 16);
    r.w = (unsigned)pos;
    temp[e] = r;  // coalesced
  } else {
    int isbf = *flagp;
    int lane = threadIdx.x & 63;
    int node = (bid - fillBlocks) * 4 + (threadIdx.x >> 6);
    if (node >= n) return;
    int idx = node * 64 + lane;
    unsigned int lo = f2b(ldf(X0, idx, isbf)) | ((unsigned int)f2b(ldf(X1, idx, isbf)) << 16);
    unsigned int hi = f2b(ldf(X2, idx, isbf)) | ((unsigned int)f2b(ldf(X3, idx, isbf)) << 16);
    uint2 g = make_uint2(lo, hi);
    *(uint2*)(Xg + (size_t)node * 256 + lane * 4) = g;
  }
}

// ---------- 2: single-block exclusive scan (replaces scan1+scan2+scan3) ----------
// 1024 threads x 98-element contiguous chunks; thread sums, one LDS block-scan,
// second pass writes off[]. 400KB x3 through L2 on one CU ~ 5-10us, cheaper
// than 3 launches + 2 gaps.
__global__ __launch_bounds__(1024) void k_scan(const int* __restrict__ cnt,
                                               int* __restrict__ off, int n) {
  __shared__ int s[1024];
  const int C = 98;  // 1024*98 = 100352 >= N
  int t = threadIdx.x;
  int base = t * C;
  int end = min(base + C, n);
  int sum = 0;
  for (int i = base; i < end; ++i) sum += cnt[i];
  s[t] = sum;
  __syncthreads();
  for (int d = 1; d < 1024; d <<= 1) {
    int tmp = (t >= d) ? s[t - d] : 0;
    __syncthreads();
    s[t] += tmp;
    __syncthreads();
  }
  int run = s[t] - sum;  // exclusive prefix of this thread's chunk
  for (int i = base; i < end; ++i) {
    int v = cnt[i];
    off[i] = run;
    run += v;
  }
  if (t == 1023) off[n] = s[1023];
}

// ---------- 3: atomic-free scatter: recs[off[d]+pos] = temp[e] ----------
__global__ void k_scatter(const int* __restrict__ ei, const uint4* __restrict__ temp,
                          const int* __restrict__ off, uint4* __restrict__ recs, int ne) {
  int e = blockIdx.x * 256 + threadIdx.x;
  if (e >= ne) return;
  uint4 r = temp[e];
  int d = ei[ne + e];
  int pos = (int)r.w;
  recs[off[d] + pos] = r;  // k_agg ignores .w
}

// ---------- 4: quaternion aggregation — wave = aligned 4-node quad (control) ----------
#if __has_builtin(__builtin_amdgcn_fdot2_f32_bf16)
#define USE_DOT2 1
#else
#define USE_DOT2 0
#endif
__global__ __launch_bounds__(128, 8) void k_agg(
    const unsigned short* __restrict__ Xg, const int* __restrict__ off,
    const uint4* __restrict__ recs, unsigned short* __restrict__ Tf, int nnodes) {
  __shared__ unsigned short tl4[2][4][256];
  int lane = threadIdx.x & 63;
  int w = threadIdx.x >> 6;
  int gq = blockIdx.x * 2 + w;  // quad index: nodes gq*4 .. gq*4+3
  int n0 = gq * 4;
  if (n0 >= nnodes) return;

  int o_[5];
#pragma unroll
  for (int i = 0; i < 5; i++) o_[i] = __builtin_amdgcn_readfirstlane(off[n0 + i]);

#pragma unroll
  for (int n = 0; n < 4; ++n) {
    int rs = o_[n], re = o_[n + 1];
    float tr = 0.f, ti = 0.f, tj = 0.f, tk = 0.f;

    auto qacc = [&](uint2 g, unsigned mx, unsigned my) {
#if USE_DOT2
      unsigned a = mx, b = my;                    // (mr,mi) (mj,mk) packed bf16x2
      unsigned sa = (a >> 16) | (a << 16);        // (mi, mr)
      unsigned sb = (b >> 16) | (b << 16);        // (mk, mj)
      unsigned A1 = a ^ 0x80000000u;              // (mr, -mi)
      unsigned A2 = b ^ 0x80008000u;              // (-mj, -mk)
      unsigned B2 = sb ^ 0x00008000u;             // (-mk, mj)
      unsigned D2 = sb ^ 0x80000000u;             // (mk, -mj)
      s16x2 gx = u2s(g.x), gy = u2s(g.y);         // (xr,xi), (xj,xk)
      tr = __builtin_amdgcn_fdot2_f32_bf16(u2s(A1), gx, tr, false);
      tr = __builtin_amdgcn_fdot2_f32_bf16(u2s(A2), gy, tr, false);
      ti = __builtin_amdgcn_fdot2_f32_bf16(u2s(sa), gx, ti, false);
      ti = __builtin_amdgcn_fdot2_f32_bf16(u2s(B2), gy, ti, false);
      tj = __builtin_amdgcn_fdot2_f32_bf16(u2s(b),  gx, tj, false);
      tj = __builtin_amdgcn_fdot2_f32_bf16(u2s(A1), gy, tj, false);
      tk = __builtin_amdgcn_fdot2_f32_bf16(u2s(D2), gx, tk, false);
      tk = __builtin_amdgcn_fdot2_f32_bf16(u2s(sa), gy, tk, false);
#else
      float mr = __uint_as_float(mx << 16), mi = __uint_as_float(mx & 0xffff0000u);
      float mj = __uint_as_float(my << 16), mk = __uint_as_float(my & 0xffff0000u);
      float xr = __uint_as_float(g.x << 16), xi = __uint_as_float(g.x & 0xffff0000u);
      float xj = __uint_as_float(g.y << 16), xk = __uint_as_float(g.y & 0xffff0000u);
      tr += mr * xr - mi * xi - mj * xj - mk * xk;
      ti += mr * xi + mi * xr + mj * xk - mk * xj;
      tj += mr * xj - mi * xk + mj * xr + mk * xi;
      tk += mr * xk + mi * xj - mj * xi + mk * xr;
#endif
    };

    int e = rs;
    for (; e + 8 <= re; e += 8) {
      uint4 r[8];
#pragma unroll
      for (int u = 0; u < 8; u++) r[u] = recs[e + u];   // uniform address
      int ss[8];
      unsigned sx[8], sy[8];
#pragma unroll
      for (int u = 0; u < 8; u++) {
        ss[u] = __builtin_amdgcn_readfirstlane((int)r[u].x);
        sx[u] = __builtin_amdgcn_readfirstlane(r[u].y);
        sy[u] = __builtin_amdgcn_readfirstlane(r[u].z);
      }
      uint2 g[8];
#pragma unroll
      for (int u = 0; u < 8; u++)
        g[u] = *(const uint2*)(Xg + (size_t)ss[u] * 256 + lane * 4);  // SGPR base
#pragma unroll
      for (int u = 0; u < 8; u++) qacc(g[u], sx[u], sy[u]);
    }
    for (; e < re; ++e) {
      uint4 r = recs[e];
      int s = __builtin_amdgcn_readfirstlane((int)r.x);
      unsigned mx = __builtin_amdgcn_readfirstlane(r.y);
      unsigned my = __builtin_amdgcn_readfirstlane(r.z);
      uint2 g0 = *(const uint2*)(Xg + (size_t)s * 256 + lane * 4);
      qacc(g0, mx, my);
    }

    tl4[w][n][lane] = f2b(tr);
    tl4[w][n][64 + lane] = f2b(ti);
    tl4[w][n][128 + lane] = f2b(tj);
    tl4[w][n][192 + lane] = f2b(tk);
  }
  __builtin_amdgcn_wave_barrier();

  // quad write: 128 x 16B chunks = 32 full 64B lines; 2 chunks per lane.
  size_t blk = (size_t)(gq >> 2) * 4096;
  int qi = gq & 3;
#pragma unroll
  for (int h = 0; h < 2; ++h) {
    int m = h * 64 + lane;
    int n = m & 3, l = m >> 2;
    uint4 v = *(const uint4*)&tl4[w][n][l * 8];
    size_t o = blk + (size_t)(l >> 2) * 512 + (l & 3) * 128 + qi * 32 + n * 8;
    *(uint4*)(Tf + o) = v;
  }
}

// ---------- 6: quaternion-structured MFMA GEMM, one barrier ----------
// mode 1: halves write disjoint P[node*8 + 0..3] / P[node*8 + 4..7] (plain
// float4 stores, no atomics, no memset); k_query sums the two quads.
__global__ __launch_bounds__(256, 2) void k_gemm(
    const unsigned short* __restrict__ A, const unsigned short* __restrict__ Wq,
    const float* __restrict__ bias, int M, int mode,
    unsigned short* __restrict__ XgOut,
    float* __restrict__ P, const void* Cw, const int* __restrict__ flagp) {
  __shared__ unsigned short Wsm[16384];  // 32 KB

  int t = threadIdx.x;
  int lane = t & 63;
  int w = t >> 6;
  int l15 = lane & 15, quad = lane >> 4;
  int m0 = blockIdx.x * 64;
  int hh = (w & 1) * 32;

#pragma unroll
  for (int i = 0; i < 8; i++)
    gload16((const char*)Wq + (size_t)(i * 256 + t) * 16,
            (char*)Wsm + (size_t)(i * 256 + w * 64) * 16);
  __syncthreads();

  short8 av[2][8];
  int n16 = blockIdx.x * 4 + (w >> 1) * 2;
#pragma unroll
  for (int mi = 0; mi < 2; mi++)
#pragma unroll
    for (int kc = 0; kc < 8; kc++)
      av[mi][kc] = *(const short8*)(A + (size_t)(n16 + mi) * 4096 + kc * 512 + lane * 8);

  f32x4 acc[2][4][2];
#pragma unroll
  for (int mi = 0; mi < 2; mi++)
#pragma unroll
    for (int c = 0; c < 4; c++)
#pragma unroll
      for (int hb = 0; hb < 2; hb++) acc[mi][c][hb] = (f32x4){0.f, 0.f, 0.f, 0.f};

#pragma unroll
  for (int kc = 0; kc < 8; kc++) {
    int a = kc >> 1;
    short8 bv[4][2];
#pragma unroll
    for (int c = 0; c < 4; c++) {
      int w4 = a ^ c;
      int neg = (0x3950 >> (a * 4 + c)) & 1;
#pragma unroll
      for (int hb = 0; hb < 2; hb++) {
        int h = hh + hb * 16 + l15;
        int lc = ((kc & 1) * 4 + quad) ^ (l15 & 7);
        short8 bb = *(const short8*)&Wsm[(w4 * 64 + h) * 64 + lc * 8];
        if (neg) {
          uint4 u = *(uint4*)&bb;
          u.x ^= 0x80008000u; u.y ^= 0x80008000u;
          u.z ^= 0x80008000u; u.w ^= 0x80008000u;
          bb = *(short8*)&u;
        }
        bv[c][hb] = bb;
      }
    }
#pragma unroll
    for (int mi = 0; mi < 2; mi++)
#pragma unroll
      for (int c = 0; c < 4; c++)
#pragma unroll
        for (int hb = 0; hb < 2; hb++)
          acc[mi][c][hb] =
              __builtin_amdgcn_mfma_f32_16x16x32_bf16(av[mi][kc], bv[c][hb], acc[mi][c][hb], 0, 0, 0);
  }

  float bias_v[4][2];
#pragma unroll
  for (int c = 0; c < 4; c++)
#pragma unroll
    for (int hb = 0; hb < 2; hb++) bias_v[c][hb] = bias[c * 64 + hh + hb * 16 + l15];

  if (mode == 0) {
#pragma unroll
    for (int mi = 0; mi < 2; mi++) {
#pragma unroll
      for (int hb = 0; hb < 2; hb++) {
#pragma unroll
        for (int r = 0; r < 4; r++) {
          int node = m0 + (w >> 1) * 32 + mi * 16 + quad * 4 + r;
          unsigned int lo =
              f2b(fmaxf(acc[mi][0][hb][r] + bias_v[0][hb], 0.f)) |
              ((unsigned int)f2b(fmaxf(acc[mi][1][hb][r] + bias_v[1][hb], 0.f)) << 16);
          unsigned int hi =
              f2b(fmaxf(acc[mi][2][hb][r] + bias_v[2][hb], 0.f)) |
              ((unsigned int)f2b(fmaxf(acc[mi][3][hb][r] + bias_v[3][hb], 0.f)) << 16);
          *(uint2*)(XgOut + (size_t)node * 256 + (hh + hb * 16 + l15) * 4) =
              make_uint2(lo, hi);
        }
      }
    }
  } else {
    int isbf = *flagp;
    float cw[4][2][4];
#pragma unroll
    for (int c = 0; c < 4; c++)
#pragma unroll
      for (int hb = 0; hb < 2; hb++) {
        int h = hh + hb * 16 + l15;
#pragma unroll
        for (int d = 0; d < 2; d++)
#pragma unroll
          for (int e = 0; e < 2; e++)
            cw[c][hb][e + 2 * d] = ldf(Cw, d * 512 + c * 128 + e * 64 + h, isbf);
      }
    float* Pout = P + ((hh == 0) ? 0 : 4);
#pragma unroll
    for (int mi = 0; mi < 2; mi++) {
#pragma unroll
      for (int r = 0; r < 4; r++) {
        int node = m0 + (w >> 1) * 32 + mi * 16 + quad * 4 + r;
        float pd0 = 0.f, pd1 = 0.f, pd2 = 0.f, pd3 = 0.f;
#pragma unroll
        for (int c = 0; c < 4; c++)
#pragma unroll
          for (int hb = 0; hb < 2; hb++) {
            float v = fmaxf(acc[mi][c][hb][r] + bias_v[c][hb], 0.f);
            pd0 += v * cw[c][hb][0];
            pd1 += v * cw[c][hb][1];
            pd2 += v * cw[c][hb][2];
            pd3 += v * cw[c][hb][3];
          }
#pragma unroll
        for (int o = 1; o < 16; o <<= 1) {
          pd0 += __shfl_xor(pd0, o);
          pd1 += __shfl_xor(pd1, o);
          pd2 += __shfl_xor(pd2, o);
          pd3 += __shfl_xor(pd3, o);
        }
        if (l15 == 0 && node < M) {
          f32x4 st = {pd0, pd1, pd2, pd3};
          *(f32x4*)(Pout + (size_t)node * 8) = st;   // disjoint per half
        }
      }
    }
  }
}

// ---------- 8: per-query logits + log_softmax (P halves at +0/+4) ----------
__global__ void k_query(const int* __restrict__ qe, const float* __restrict__ P,
                        const void* Cb, const int* __restrict__ flagp,
                        void* out, int nq) {
  int isbf = *flagp;
  int q = blockIdx.x * 256 + threadIdx.x;
  if (q >= nq) return;
  int q0 = qe[q * 2], q1 = qe[q * 2 + 1];
  f32x4 a0 = *(const f32x4*)(P + (size_t)q0 * 8);
  f32x4 b0 = *(const f32x4*)(P + (size_t)q0 * 8 + 4);
  f32x4 a1 = *(const f32x4*)(P + (size_t)q1 * 8);
  f32x4 b1 = *(const f32x4*)(P + (size_t)q1 * 8 + 4);
  float l0 = (a0[0] + b0[0]) + (a1[1] + b1[1]) + ldf(Cb, 0, isbf);
  float l1 = (a0[2] + b0[2]) + (a1[3] + b1[3]) + ldf(Cb, 1, isbf);
  float m = fmaxf(l0, l1);
  float lse = m + logf(expf(l0 - m) + expf(l1 - m));
  float o0 = l0 - lse, o1 = l1 - lse;
  if (isbf) {
    __hip_bfloat16* o = (__hip_bfloat16*)out;
    o[q * 2] = __float2bfloat16(o0);
    o[q * 2 + 1] = __float2bfloat16(o1);
  } else {
    float* o = (float*)out;
    o[q * 2] = o0;
    o[q * 2 + 1] = o1;
  }
}

extern "C" void kernel_launch(void* const* d_in, const int* in_sizes, int n_in,
                              void* d_out, int out_size, void* d_ws, size_t ws_size,
                              hipStream_t stream) {
  const int N = N_NODESC, NE = N_EDGESC, NQ = N_QUERYC;
  const int NPAD = 100224;  // >= 1563*64 = 100032

  char* w = (char*)d_ws;
  auto alloc = [&](size_t bytes) -> void* {
    void* p = (void*)w;
    w += (bytes + 255) & ~(size_t)255;
    return p;
  };
  int* flag       = (int*)alloc(4);
  int* offsets    = (int*)alloc((size_t)(N + 1) * 4);
  int* cnt        = (int*)alloc((size_t)N * 4);
  uint4* recs     = (uint4*)alloc((size_t)NE * 16);
  unsigned short* Tf = (unsigned short*)alloc((size_t)NPAD * 256 * 2);
  unsigned short* Xg = (unsigned short*)alloc((size_t)NPAD * 256 * 2);
  unsigned short* Wq1 = (unsigned short*)alloc(16384 * 2);
  unsigned short* Wq2 = (unsigned short*)alloc(16384 * 2);
  float* bcat1    = (float*)alloc(256 * 4);
  float* bcat2    = (float*)alloc(256 * 4);
  float* P        = (float*)alloc((size_t)N * 8 * 4);
  uint4* temp     = (uint4*)Tf;  // alias: temp consumed by k_scatter before k_agg writes Tf
  (void)ws_size; (void)n_in; (void)in_sizes; (void)out_size;

  const int* ei = (const int*)d_in[8];

  // setup: zero cnt ∪ sniff ∪ both weight swizzles (one launch)
  int nzBlocks = (N + 255) / 256;  // 391
  k_setup<<<nzBlocks + 1 + 128, 256, 0, stream>>>(
      d_in[0], flag, cnt, N,
      d_in[10], d_in[11], d_in[12], d_in[13],
      Wq1, bcat1, Wq2, bcat2, nzBlocks);

  // single atomic pass (counts + positions + records) ∪ ilv
  int fillBlocks = (NE + 255) / 256;          // 3907
  int ilvBlocks = (N + 3) / 4;                // 25000
  k_fill0_ilv<<<fillBlocks + ilvBlocks, 256, 0, stream>>>(
      ei, d_in[4], d_in[5], d_in[6], d_in[7], cnt, temp, NE, fillBlocks,
      d_in[0], d_in[1], d_in[2], d_in[3], flag, Xg, N);

  // single-block scan + atomic-free scatter
  k_scan<<<1, 1024, 0, stream>>>(cnt, offsets, N);
  k_scatter<<<fillBlocks, 256, 0, stream>>>(ei, temp, offsets, recs, NE);

  int ggrid = (N + 63) / 64;
  int nquads = (N + 3) / 4;           // 25000
  int agrid = (nquads + 1) / 2;       // 12500 blocks of 128 threads

  // layer 1
  k_agg<<<agrid, 128, 0, stream>>>(Xg, offsets, recs, Tf, N);
  k_gemm<<<ggrid, 256, 0, stream>>>(Tf, Wq1, bcat1, N, 0, Xg, nullptr, nullptr, flag);

  // layer 2 (+fused readout partial dots, atomic-free interleaved P)
  k_agg<<<agrid, 128, 0, stream>>>(Xg, offsets, recs, Tf, N);
  k_gemm<<<ggrid, 256, 0, stream>>>(Tf, Wq2, bcat2, N, 1, nullptr, P, d_in[14], flag);

  // queries
  k_query<<<(NQ + 255) / 256, 256, 0, stream>>>((const int*)d_in[9], P, d_in[15],
                                                flag, d_out, NQ);
}

// Round 10
// 462.452 us; speedup vs baseline: 1.3271x; 1.3271x over previous
//
#include <hip/hip_runtime.h>
#include <hip/hip_bf16.h>

#define N_NODESC 100000
#define N_EDGESC 1000000
#define N_QUERYC 100000

typedef short short8 __attribute__((ext_vector_type(8)));
typedef short s16x2 __attribute__((ext_vector_type(2)));
typedef float f32x4 __attribute__((ext_vector_type(4)));

// ---------- dual-dtype load helper (flag: 1 = inputs are bf16, 0 = f32) ----------
__device__ __forceinline__ float ldf(const void* p, int i, int isbf) {
  return isbf ? __bfloat162float(((const __hip_bfloat16*)p)[i])
              : ((const float*)p)[i];
}
__device__ __forceinline__ unsigned short f2b(float x) {
  __hip_bfloat16 h = __float2bfloat16(x);
  return *(unsigned short*)&h;
}
__device__ __forceinline__ s16x2 u2s(unsigned u) {
  union { unsigned u; s16x2 s; } c; c.u = u; return c.s;
}
__device__ __forceinline__ void gload16(const void* g, void* l) {
  __builtin_amdgcn_global_load_lds(
      (const __attribute__((address_space(1))) void*)g,
      (__attribute__((address_space(3))) void*)l, 16, 0, 0);
}

// ---------- 0: fused setup — cnt zeroing ∪ sniff ∪ BOTH weight swizzles ----------
// R9 verified: this fusion is clean (regression there was k_scan alone).
__global__ __launch_bounds__(256) void k_setup(
    const void* x, int* flag, int* cnt, int n,
    const void* W1, const void* b1, const void* W2, const void* b2,
    unsigned short* __restrict__ Wq1, float* __restrict__ bcat1,
    unsigned short* __restrict__ Wq2, float* __restrict__ bcat2, int nzBlocks) {
  int bid = blockIdx.x;
  int t = threadIdx.x;
  if (bid < nzBlocks) {
    int i = bid * 256 + t;
    if (i < n) cnt[i] = 0;
    return;
  }
  // local sniff (deterministic, same result in every block)
  __shared__ int scnt;
  if (t == 0) scnt = 0;
  __syncthreads();
  const unsigned short* h = (const unsigned short*)x;
  int local = 0;
  for (int i = t; i < 4096; i += 256) {
    int e = (h[i] >> 7) & 0xFF;
    if (e >= 107 && e <= 133) local++;
  }
  atomicAdd(&scnt, local);
  __syncthreads();
  int isbf = (scnt >= 3482) ? 1 : 0;
  if (bid == nzBlocks) {
    if (t == 0) *flag = isbf;
    return;
  }
  int wb = bid - nzBlocks - 1;  // 0..127
  int layer = wb >> 6;
  const void* W = layer ? W2 : W1;
  const void* b = layer ? b2 : b1;
  unsigned short* Wq = layer ? Wq2 : Wq1;
  float* bcat = layer ? bcat2 : bcat1;
  int tt = (wb & 63) * 256 + t;  // 0..16383
  int w4 = tt >> 12;
  int hh = (tt >> 6) & 63;
  int kk = tt & 63;
  int s = (kk >> 3) ^ (hh & 7);
  Wq[(w4 * 64 + hh) * 64 + s * 8 + (kk & 7)] = f2b(ldf(W, w4 * 4096 + kk * 64 + hh, isbf));
  if (tt < 256) bcat[tt] = ldf(b, tt, isbf);
}

// ---------- 1: fused single-atomic-pass fill0 ∪ interleave inputs ----------
// R8 verified: 1M random device atomics ~ 70us regardless of padding.
__global__ __launch_bounds__(256) void k_fill0_ilv(
    const int* __restrict__ ei,
    const void* nr, const void* ni, const void* nj, const void* nk,
    int* __restrict__ cnt, uint4* __restrict__ temp, int ne, int fillBlocks,
    const void* X0, const void* X1, const void* X2, const void* X3,
    const int* __restrict__ flagp, unsigned short* __restrict__ Xg, int n) {
  int bid = blockIdx.x;
  if (bid < fillBlocks) {
    int isbf = *flagp;
    int e = bid * 256 + threadIdx.x;
    if (e >= ne) return;
    int s = ei[e];
    int d = ei[ne + e];
    int pos = atomicAdd(&cnt[d], 1);
    uint4 r;
    r.x = (unsigned)s;
    r.y = (unsigned)f2b(-ldf(nr, e, isbf)) | ((unsigned)f2b(-ldf(ni, e, isbf)) << 16);
    r.z = (unsigned)f2b(-ldf(nj, e, isbf)) | ((unsigned)f2b(-ldf(nk, e, isbf)) << 16);
    r.w = (unsigned)pos;
    temp[e] = r;  // coalesced
  } else {
    int isbf = *flagp;
    int lane = threadIdx.x & 63;
    int node = (bid - fillBlocks) * 4 + (threadIdx.x >> 6);
    if (node >= n) return;
    int idx = node * 64 + lane;
    unsigned int lo = f2b(ldf(X0, idx, isbf)) | ((unsigned int)f2b(ldf(X1, idx, isbf)) << 16);
    unsigned int hi = f2b(ldf(X2, idx, isbf)) | ((unsigned int)f2b(ldf(X3, idx, isbf)) << 16);
    uint2 g = make_uint2(lo, hi);
    *(uint2*)(Xg + (size_t)node * 256 + lane * 4) = g;
  }
}

// ---------- 2a: per-chunk exclusive scan (R9 post-mortem: whole-chip scan, ----------
// NOT single-block — one CU walking 400KB of remote-L2 lines = 162us of latency
// serialization; 3 launches + gaps (~12us) are 13x cheaper.
__global__ void k_scan1(const int* __restrict__ cnt, int* __restrict__ off,
                        int* __restrict__ partials, int n) {
  __shared__ int s[1024];
  int t = threadIdx.x;
  int idx = blockIdx.x * 1024 + t;
  int v = (idx < n) ? cnt[idx] : 0;
  s[t] = v;
  __syncthreads();
  for (int d = 1; d < 1024; d <<= 1) {
    int tmp = (t >= d) ? s[t - d] : 0;
    __syncthreads();
    s[t] += tmp;
    __syncthreads();
  }
  if (idx < n) off[idx] = s[t] - v;
  if (t == 1023) partials[blockIdx.x] = s[1023];
}

// ---------- 2b: scan chunk totals ----------
__global__ void k_scan2(const int* __restrict__ partials, int* __restrict__ pref,
                        int* __restrict__ off, int nb, int npos) {
  __shared__ int s[128];
  int t = threadIdx.x;
  int v = (t < nb) ? partials[t] : 0;
  s[t] = v;
  __syncthreads();
  for (int d = 1; d < 128; d <<= 1) {
    int tmp = (t >= d) ? s[t - d] : 0;
    __syncthreads();
    s[t] += tmp;
    __syncthreads();
  }
  if (t < nb) pref[t] = s[t] - v;
  if (t == 127) off[npos] = s[127];
}

// ---------- 2c: apply chunk prefixes ----------
__global__ void k_scan3(int* __restrict__ off, const int* __restrict__ pref, int n) {
  int i = blockIdx.x * 256 + threadIdx.x;
  if (i < n) off[i] = off[i] + pref[i >> 10];
}

// ---------- 3: atomic-free scatter: recs[off[d]+pos] = temp[e] ----------
__global__ void k_scatter(const int* __restrict__ ei, const uint4* __restrict__ temp,
                          const int* __restrict__ off, uint4* __restrict__ recs, int ne) {
  int e = blockIdx.x * 256 + threadIdx.x;
  if (e >= ne) return;
  uint4 r = temp[e];
  int d = ei[ne + e];
  int pos = (int)r.w;
  recs[off[d] + pos] = r;  // k_agg ignores .w
}

// ---------- 4: quaternion aggregation — wave = aligned 4-node quad (control) ----------
#if __has_builtin(__builtin_amdgcn_fdot2_f32_bf16)
#define USE_DOT2 1
#else
#define USE_DOT2 0
#endif
__global__ __launch_bounds__(128, 8) void k_agg(
    const unsigned short* __restrict__ Xg, const int* __restrict__ off,
    const uint4* __restrict__ recs, unsigned short* __restrict__ Tf, int nnodes) {
  __shared__ unsigned short tl4[2][4][256];
  int lane = threadIdx.x & 63;
  int w = threadIdx.x >> 6;
  int gq = blockIdx.x * 2 + w;  // quad index: nodes gq*4 .. gq*4+3
  int n0 = gq * 4;
  if (n0 >= nnodes) return;

  int o_[5];
#pragma unroll
  for (int i = 0; i < 5; i++) o_[i] = __builtin_amdgcn_readfirstlane(off[n0 + i]);

#pragma unroll
  for (int n = 0; n < 4; ++n) {
    int rs = o_[n], re = o_[n + 1];
    float tr = 0.f, ti = 0.f, tj = 0.f, tk = 0.f;

    auto qacc = [&](uint2 g, unsigned mx, unsigned my) {
#if USE_DOT2
      unsigned a = mx, b = my;                    // (mr,mi) (mj,mk) packed bf16x2
      unsigned sa = (a >> 16) | (a << 16);        // (mi, mr)
      unsigned sb = (b >> 16) | (b << 16);        // (mk, mj)
      unsigned A1 = a ^ 0x80000000u;              // (mr, -mi)
      unsigned A2 = b ^ 0x80008000u;              // (-mj, -mk)
      unsigned B2 = sb ^ 0x00008000u;             // (-mk, mj)
      unsigned D2 = sb ^ 0x80000000u;             // (mk, -mj)
      s16x2 gx = u2s(g.x), gy = u2s(g.y);         // (xr,xi), (xj,xk)
      tr = __builtin_amdgcn_fdot2_f32_bf16(u2s(A1), gx, tr, false);
      tr = __builtin_amdgcn_fdot2_f32_bf16(u2s(A2), gy, tr, false);
      ti = __builtin_amdgcn_fdot2_f32_bf16(u2s(sa), gx, ti, false);
      ti = __builtin_amdgcn_fdot2_f32_bf16(u2s(B2), gy, ti, false);
      tj = __builtin_amdgcn_fdot2_f32_bf16(u2s(b),  gx, tj, false);
      tj = __builtin_amdgcn_fdot2_f32_bf16(u2s(A1), gy, tj, false);
      tk = __builtin_amdgcn_fdot2_f32_bf16(u2s(D2), gx, tk, false);
      tk = __builtin_amdgcn_fdot2_f32_bf16(u2s(sa), gy, tk, false);
#else
      float mr = __uint_as_float(mx << 16), mi = __uint_as_float(mx & 0xffff0000u);
      float mj = __uint_as_float(my << 16), mk = __uint_as_float(my & 0xffff0000u);
      float xr = __uint_as_float(g.x << 16), xi = __uint_as_float(g.x & 0xffff0000u);
      float xj = __uint_as_float(g.y << 16), xk = __uint_as_float(g.y & 0xffff0000u);
      tr += mr * xr - mi * xi - mj * xj - mk * xk;
      ti += mr * xi + mi * xr + mj * xk - mk * xj;
      tj += mr * xj - mi * xk + mj * xr + mk * xi;
      tk += mr * xk + mi * xj - mj * xi + mk * xr;
#endif
    };

    int e = rs;
    for (; e + 8 <= re; e += 8) {
      uint4 r[8];
#pragma unroll
      for (int u = 0; u < 8; u++) r[u] = recs[e + u];   // uniform address
      int ss[8];
      unsigned sx[8], sy[8];
#pragma unroll
      for (int u = 0; u < 8; u++) {
        ss[u] = __builtin_amdgcn_readfirstlane((int)r[u].x);
        sx[u] = __builtin_amdgcn_readfirstlane(r[u].y);
        sy[u] = __builtin_amdgcn_readfirstlane(r[u].z);
      }
      uint2 g[8];
#pragma unroll
      for (int u = 0; u < 8; u++)
        g[u] = *(const uint2*)(Xg + (size_t)ss[u] * 256 + lane * 4);  // SGPR base
#pragma unroll
      for (int u = 0; u < 8; u++) qacc(g[u], sx[u], sy[u]);
    }
    for (; e < re; ++e) {
      uint4 r = recs[e];
      int s = __builtin_amdgcn_readfirstlane((int)r.x);
      unsigned mx = __builtin_amdgcn_readfirstlane(r.y);
      unsigned my = __builtin_amdgcn_readfirstlane(r.z);
      uint2 g0 = *(const uint2*)(Xg + (size_t)s * 256 + lane * 4);
      qacc(g0, mx, my);
    }

    tl4[w][n][lane] = f2b(tr);
    tl4[w][n][64 + lane] = f2b(ti);
    tl4[w][n][128 + lane] = f2b(tj);
    tl4[w][n][192 + lane] = f2b(tk);
  }
  __builtin_amdgcn_wave_barrier();

  // quad write: 128 x 16B chunks = 32 full 64B lines; 2 chunks per lane.
  size_t blk = (size_t)(gq >> 2) * 4096;
  int qi = gq & 3;
#pragma unroll
  for (int h = 0; h < 2; ++h) {
    int m = h * 64 + lane;
    int n = m & 3, l = m >> 2;
    uint4 v = *(const uint4*)&tl4[w][n][l * 8];
    size_t o = blk + (size_t)(l >> 2) * 512 + (l & 3) * 128 + qi * 32 + n * 8;
    *(uint4*)(Tf + o) = v;
  }
}

// ---------- 6: quaternion-structured MFMA GEMM, one barrier ----------
__global__ __launch_bounds__(256, 2) void k_gemm(
    const unsigned short* __restrict__ A, const unsigned short* __restrict__ Wq,
    const float* __restrict__ bias, int M, int mode,
    unsigned short* __restrict__ XgOut,
    float* __restrict__ P, const void* Cw, const int* __restrict__ flagp) {
  __shared__ unsigned short Wsm[16384];  // 32 KB

  int t = threadIdx.x;
  int lane = t & 63;
  int w = t >> 6;
  int l15 = lane & 15, quad = lane >> 4;
  int m0 = blockIdx.x * 64;
  int hh = (w & 1) * 32;

#pragma unroll
  for (int i = 0; i < 8; i++)
    gload16((const char*)Wq + (size_t)(i * 256 + t) * 16,
            (char*)Wsm + (size_t)(i * 256 + w * 64) * 16);
  __syncthreads();

  short8 av[2][8];
  int n16 = blockIdx.x * 4 + (w >> 1) * 2;
#pragma unroll
  for (int mi = 0; mi < 2; mi++)
#pragma unroll
    for (int kc = 0; kc < 8; kc++)
      av[mi][kc] = *(const short8*)(A + (size_t)(n16 + mi) * 4096 + kc * 512 + lane * 8);

  f32x4 acc[2][4][2];
#pragma unroll
  for (int mi = 0; mi < 2; mi++)
#pragma unroll
    for (int c = 0; c < 4; c++)
#pragma unroll
      for (int hb = 0; hb < 2; hb++) acc[mi][c][hb] = (f32x4){0.f, 0.f, 0.f, 0.f};

#pragma unroll
  for (int kc = 0; kc < 8; kc++) {
    int a = kc >> 1;
    short8 bv[4][2];
#pragma unroll
    for (int c = 0; c < 4; c++) {
      int w4 = a ^ c;
      int neg = (0x3950 >> (a * 4 + c)) & 1;
#pragma unroll
      for (int hb = 0; hb < 2; hb++) {
        int h = hh + hb * 16 + l15;
        int lc = ((kc & 1) * 4 + quad) ^ (l15 & 7);
        short8 bb = *(const short8*)&Wsm[(w4 * 64 + h) * 64 + lc * 8];
        if (neg) {
          uint4 u = *(uint4*)&bb;
          u.x ^= 0x80008000u; u.y ^= 0x80008000u;
          u.z ^= 0x80008000u; u.w ^= 0x80008000u;
          bb = *(short8*)&u;
        }
        bv[c][hb] = bb;
      }
    }
#pragma unroll
    for (int mi = 0; mi < 2; mi++)
#pragma unroll
      for (int c = 0; c < 4; c++)
#pragma unroll
        for (int hb = 0; hb < 2; hb++)
          acc[mi][c][hb] =
              __builtin_amdgcn_mfma_f32_16x16x32_bf16(av[mi][kc], bv[c][hb], acc[mi][c][hb], 0, 0, 0);
  }

  float bias_v[4][2];
#pragma unroll
  for (int c = 0; c < 4; c++)
#pragma unroll
    for (int hb = 0; hb < 2; hb++) bias_v[c][hb] = bias[c * 64 + hh + hb * 16 + l15];

  if (mode == 0) {
#pragma unroll
    for (int mi = 0; mi < 2; mi++) {
#pragma unroll
      for (int hb = 0; hb < 2; hb++) {
#pragma unroll
        for (int r = 0; r < 4; r++) {
          int node = m0 + (w >> 1) * 32 + mi * 16 + quad * 4 + r;
          unsigned int lo =
              f2b(fmaxf(acc[mi][0][hb][r] + bias_v[0][hb], 0.f)) |
              ((unsigned int)f2b(fmaxf(acc[mi][1][hb][r] + bias_v[1][hb], 0.f)) << 16);
          unsigned int hi =
              f2b(fmaxf(acc[mi][2][hb][r] + bias_v[2][hb], 0.f)) |
              ((unsigned int)f2b(fmaxf(acc[mi][3][hb][r] + bias_v[3][hb], 0.f)) << 16);
          *(uint2*)(XgOut + (size_t)node * 256 + (hh + hb * 16 + l15) * 4) =
              make_uint2(lo, hi);
        }
      }
    }
  } else {
    int isbf = *flagp;
    float cw[4][2][4];
#pragma unroll
    for (int c = 0; c < 4; c++)
#pragma unroll
      for (int hb = 0; hb < 2; hb++) {
        int h = hh + hb * 16 + l15;
#pragma unroll
        for (int d = 0; d < 2; d++)
#pragma unroll
          for (int e = 0; e < 2; e++)
            cw[c][hb][e + 2 * d] = ldf(Cw, d * 512 + c * 128 + e * 64 + h, isbf);
      }
    float* Pout = P + ((hh == 0) ? 0 : 4);
#pragma unroll
    for (int mi = 0; mi < 2; mi++) {
#pragma unroll
      for (int r = 0; r < 4; r++) {
        int node = m0 + (w >> 1) * 32 + mi * 16 + quad * 4 + r;
        float pd0 = 0.f, pd1 = 0.f, pd2 = 0.f, pd3 = 0.f;
#pragma unroll
        for (int c = 0; c < 4; c++)
#pragma unroll
          for (int hb = 0; hb < 2; hb++) {
            float v = fmaxf(acc[mi][c][hb][r] + bias_v[c][hb], 0.f);
            pd0 += v * cw[c][hb][0];
            pd1 += v * cw[c][hb][1];
            pd2 += v * cw[c][hb][2];
            pd3 += v * cw[c][hb][3];
          }
#pragma unroll
        for (int o = 1; o < 16; o <<= 1) {
          pd0 += __shfl_xor(pd0, o);
          pd1 += __shfl_xor(pd1, o);
          pd2 += __shfl_xor(pd2, o);
          pd3 += __shfl_xor(pd3, o);
        }
        if (l15 == 0 && node < M) {
          f32x4 st = {pd0, pd1, pd2, pd3};
          *(f32x4*)(Pout + (size_t)node * 8) = st;   // disjoint per half
        }
      }
    }
  }
}

// ---------- 8: per-query logits + log_softmax (P halves at +0/+4) ----------
__global__ void k_query(const int* __restrict__ qe, const float* __restrict__ P,
                        const void* Cb, const int* __restrict__ flagp,
                        void* out, int nq) {
  int isbf = *flagp;
  int q = blockIdx.x * 256 + threadIdx.x;
  if (q >= nq) return;
  int q0 = qe[q * 2], q1 = qe[q * 2 + 1];
  f32x4 a0 = *(const f32x4*)(P + (size_t)q0 * 8);
  f32x4 b0 = *(const f32x4*)(P + (size_t)q0 * 8 + 4);
  f32x4 a1 = *(const f32x4*)(P + (size_t)q1 * 8);
  f32x4 b1 = *(const f32x4*)(P + (size_t)q1 * 8 + 4);
  float l0 = (a0[0] + b0[0]) + (a1[1] + b1[1]) + ldf(Cb, 0, isbf);
  float l1 = (a0[2] + b0[2]) + (a1[3] + b1[3]) + ldf(Cb, 1, isbf);
  float m = fmaxf(l0, l1);
  float lse = m + logf(expf(l0 - m) + expf(l1 - m));
  float o0 = l0 - lse, o1 = l1 - lse;
  if (isbf) {
    __hip_bfloat16* o = (__hip_bfloat16*)out;
    o[q * 2] = __float2bfloat16(o0);
    o[q * 2 + 1] = __float2bfloat16(o1);
  } else {
    float* o = (float*)out;
    o[q * 2] = o0;
    o[q * 2 + 1] = o1;
  }
}

extern "C" void kernel_launch(void* const* d_in, const int* in_sizes, int n_in,
                              void* d_out, int out_size, void* d_ws, size_t ws_size,
                              hipStream_t stream) {
  const int N = N_NODESC, NE = N_EDGESC, NQ = N_QUERYC;
  const int NPAD = 100224;  // >= 1563*64 = 100032

  char* w = (char*)d_ws;
  auto alloc = [&](size_t bytes) -> void* {
    void* p = (void*)w;
    w += (bytes + 255) & ~(size_t)255;
    return p;
  };
  int* flag       = (int*)alloc(4);
  int* offsets    = (int*)alloc((size_t)(N + 1) * 4);
  int* cnt        = (int*)alloc((size_t)N * 4);
  int* partials   = (int*)alloc(128 * 4);
  int* pref       = (int*)alloc(128 * 4);
  uint4* recs     = (uint4*)alloc((size_t)NE * 16);
  unsigned short* Tf = (unsigned short*)alloc((size_t)NPAD * 256 * 2);
  unsigned short* Xg = (unsigned short*)alloc((size_t)NPAD * 256 * 2);
  unsigned short* Wq1 = (unsigned short*)alloc(16384 * 2);
  unsigned short* Wq2 = (unsigned short*)alloc(16384 * 2);
  float* bcat1    = (float*)alloc(256 * 4);
  float* bcat2    = (float*)alloc(256 * 4);
  float* P        = (float*)alloc((size_t)N * 8 * 4);
  uint4* temp     = (uint4*)Tf;  // alias: temp consumed by k_scatter before k_agg writes Tf
  (void)ws_size; (void)n_in; (void)in_sizes; (void)out_size;

  const int* ei = (const int*)d_in[8];

  // setup: zero cnt ∪ sniff ∪ both weight swizzles (one launch)
  int nzBlocks = (N + 255) / 256;  // 391
  k_setup<<<nzBlocks + 1 + 128, 256, 0, stream>>>(
      d_in[0], flag, cnt, N,
      d_in[10], d_in[11], d_in[12], d_in[13],
      Wq1, bcat1, Wq2, bcat2, nzBlocks);

  // single atomic pass (counts + positions + records) ∪ ilv
  int fillBlocks = (NE + 255) / 256;          // 3907
  int ilvBlocks = (N + 3) / 4;                // 25000
  k_fill0_ilv<<<fillBlocks + ilvBlocks, 256, 0, stream>>>(
      ei, d_in[4], d_in[5], d_in[6], d_in[7], cnt, temp, NE, fillBlocks,
      d_in[0], d_in[1], d_in[2], d_in[3], flag, Xg, N);

  // whole-chip hierarchical scan + atomic-free scatter
  k_scan1<<<(N + 1023) / 1024, 1024, 0, stream>>>(cnt, offsets, partials, N);
  k_scan2<<<1, 128, 0, stream>>>(partials, pref, offsets, (N + 1023) / 1024, N);
  k_scan3<<<(N + 255) / 256, 256, 0, stream>>>(offsets, pref, N);
  k_scatter<<<fillBlocks, 256, 0, stream>>>(ei, temp, offsets, recs, NE);

  int ggrid = (N + 63) / 64;
  int nquads = (N + 3) / 4;           // 25000
  int agrid = (nquads + 1) / 2;       // 12500 blocks of 128 threads

  // layer 1
  k_agg<<<agrid, 128, 0, stream>>>(Xg, offsets, recs, Tf, N);
  k_gemm<<<ggrid, 256, 0, stream>>>(Tf, Wq1, bcat1, N, 0, Xg, nullptr, nullptr, flag);

  // layer 2 (+fused readout partial dots, atomic-free interleaved P)
  k_agg<<<agrid, 128, 0, stream>>>(Xg, offsets, recs, Tf, N);
  k_gemm<<<ggrid, 256, 0, stream>>>(Tf, Wq2, bcat2, N, 1, nullptr, P, d_in[14], flag);

  // queries
  k_query<<<(NQ + 255) / 256, 256, 0, stream>>>((const int*)d_in[9], P, d_in[15],
                                                flag, d_out, NQ);
}